// Round 8
// baseline (26019.498 us; speedup 1.0000x reference)
//
#include <hip/hip_runtime.h>
#include <hip/hip_cooperative_groups.h>
namespace cg = cooperative_groups;

typedef unsigned short u16;
typedef unsigned int   u32;
typedef _Float16 f16;
typedef f16   f16x8 __attribute__((ext_vector_type(8)));
typedef float f32x4 __attribute__((ext_vector_type(4)));

#define B_  64
#define L_  384
#define CS  512   // SRC_DIM
#define H_  512
#define E_  256
#define NC  250
#define T_  127
#define LPAD 264  // LDS ctx stride in f16

// dynamic LDS layout (bytes)
#define SFL_OFF 0                  // [96][512] f16 = 98304
#define WSC_OFF 98304              // [512] f32 = 2048
#define SCR_OFF 100352             // scratch region, 54528 B
#define LDS_TOTAL 154880

__device__ __forceinline__ float h2f(u16 u){ f16 h; __builtin_memcpy(&h,&u,2); return (float)h; }
__device__ __forceinline__ u16  f2h(float f){ f16 h=(f16)f; u16 u; __builtin_memcpy(&u,&h,2); return u; }
__device__ __forceinline__ float wredsum_b(float v){
#pragma unroll
  for (int o=32;o>0;o>>=1) v += __shfl_xor(v, o, 64);
  return v;
}
__device__ __forceinline__ float tanh_f(float x){
  x = fminf(fmaxf(x, -15.f), 15.f);
  float e = __expf(2.f*x);
  return (e-1.f)/(e+1.f);
}
__device__ __forceinline__ float sigm_f(float x){
  x = fminf(fmaxf(x, -30.f), 30.f);
  return 1.f/(1.f+__expf(-x));
}

// ---------------- one-time converters ----------------
__global__ __launch_bounds__(256) void k_cvt(const float* __restrict__ in, f16* __restrict__ o, size_t n){
  size_t i = (size_t)blockIdx.x*256 + threadIdx.x;
  if (i < n) o[i] = (f16)in[i];
}
__global__ __launch_bounds__(256) void k_packwg(const float* __restrict__ Wih,
    const float* __restrict__ Whh, f16* __restrict__ Wg){
  int i = blockIdx.x*256 + threadIdx.x;
  if (i < 2048*1280){
    int r = i / 1280, c = i - r*1280;
    float v = (c < 768) ? Wih[(size_t)r*768 + c] : Whh[(size_t)r*512 + (c-768)];
    Wg[i] = (f16)v;
  }
}
// Xg layout: [b][768]: emb at 0..256, h at 256..768
__global__ __launch_bounds__(256) void k_initx(const int* __restrict__ text,
    const float* __restrict__ embt, f16* __restrict__ X0){
  int b = blockIdx.x, col = threadIdx.x;
  int tok = text[b*T_];
  X0[(size_t)b*768 + col] = (f16)embt[(size_t)tok*E_ + col];
}

// ---------------- GEMM1: src_feat = src @ Wi2h^T (f32 in, f16 out)
__global__ __launch_bounds__(256) void gemm_srcfeat(
    const float* __restrict__ A, const float* __restrict__ W, u16* __restrict__ Cd,
    int M, int N, int K)
{
  __shared__ float As[8][128+4];
  __shared__ float Ws[8][128+4];
  const int tid = threadIdx.x;
  const int bm = blockIdx.x * 128;
  const int bn = blockIdx.y * 128;
  const int lr = tid >> 1;
  const int lc = (tid & 1) * 4;
  const int ty = tid >> 4, tx = tid & 15;
  float acc[8][8];
#pragma unroll
  for (int i=0;i<8;i++)
#pragma unroll
    for (int j=0;j<8;j++) acc[i][j]=0.f;

  for (int k0=0;k0<K;k0+=8){
    float4 va = *(const float4*)(A + (size_t)(bm+lr)*K + k0 + lc);
    float4 vw = *(const float4*)(W + (size_t)(bn+lr)*K + k0 + lc);
    As[lc+0][lr]=va.x; As[lc+1][lr]=va.y; As[lc+2][lr]=va.z; As[lc+3][lr]=va.w;
    Ws[lc+0][lr]=vw.x; Ws[lc+1][lr]=vw.y; Ws[lc+2][lr]=vw.z; Ws[lc+3][lr]=vw.w;
    __syncthreads();
#pragma unroll
    for (int k=0;k<8;k++){
      float a[8], w[8];
#pragma unroll
      for (int i=0;i<8;i++) a[i]=As[k][ty*8+i];
#pragma unroll
      for (int j=0;j<8;j++) w[j]=Ws[k][tx*8+j];
#pragma unroll
      for (int i=0;i<8;i++)
#pragma unroll
        for (int j=0;j<8;j++) acc[i][j] += a[i]*w[j];
    }
    __syncthreads();
  }
#pragma unroll
  for (int i=0;i<8;i++){
    int m = bm + ty*8 + i;
    u16* cp = Cd + (size_t)m*N + bn + tx*8;
    ushort4 o0, o1;
    o0.x=f2h(acc[i][0]); o0.y=f2h(acc[i][1]); o0.z=f2h(acc[i][2]); o0.w=f2h(acc[i][3]);
    o1.x=f2h(acc[i][4]); o1.y=f2h(acc[i][5]); o1.z=f2h(acc[i][6]); o1.w=f2h(acc[i][7]);
    *(ushort4*)cp = o0;
    *(ushort4*)(cp+4) = o1;
  }
}

// ---------------- GEMM2: probs = hs @ Wgen^T + bgen (A f16, W f32, out f32)
__global__ __launch_bounds__(256) void gemm_probs(
    const u16* __restrict__ A, const float* __restrict__ W, const float* __restrict__ bias,
    float* __restrict__ Cd, int M, int N, int K)
{
  __shared__ float As[16][64+1];
  __shared__ float Ws[16][64+1];
  const int tid = threadIdx.x;
  const int bm = blockIdx.x*64, bn = blockIdx.y*64;
  const int lr = tid>>2;
  const int lc = (tid&3)*4;
  const int ty = tid>>4, tx = tid&15;
  float acc[4][4];
#pragma unroll
  for (int i=0;i<4;i++)
#pragma unroll
    for (int j=0;j<4;j++) acc[i][j]=0.f;

  for (int k0=0;k0<K;k0+=16){
    ushort4 va = *(const ushort4*)(A + (size_t)(bm+lr)*K + k0 + lc);
    As[lc+0][lr]=h2f(va.x); As[lc+1][lr]=h2f(va.y); As[lc+2][lr]=h2f(va.z); As[lc+3][lr]=h2f(va.w);
    int n = bn + lr;
    if (n < N){
      float4 vw = *(const float4*)(W + (size_t)n*K + k0 + lc);
      Ws[lc+0][lr]=vw.x; Ws[lc+1][lr]=vw.y; Ws[lc+2][lr]=vw.z; Ws[lc+3][lr]=vw.w;
    } else {
      Ws[lc+0][lr]=0.f; Ws[lc+1][lr]=0.f; Ws[lc+2][lr]=0.f; Ws[lc+3][lr]=0.f;
    }
    __syncthreads();
#pragma unroll
    for (int k=0;k<16;k++){
      float a[4], w[4];
#pragma unroll
      for (int i=0;i<4;i++) a[i]=As[k][ty*4+i];
#pragma unroll
      for (int j=0;j<4;j++) w[j]=Ws[k][tx*4+j];
#pragma unroll
      for (int i=0;i<4;i++)
#pragma unroll
        for (int j=0;j<4;j++) acc[i][j] += a[i]*w[j];
    }
    __syncthreads();
  }
#pragma unroll
  for (int i=0;i<4;i++){
    int m = bm + ty*4 + i;
#pragma unroll
    for (int j=0;j<4;j++){
      int n = bn + tx*4 + j;
      if (n < N) Cd[(size_t)m*N + n] = acc[i][j] + bias[n];
    }
  }
}

// ---------------- persistent cooperative recurrence: 256 blocks x 512 thr
// Block (b,q) holds sf[b, q*96..(q+1)*96, :] in LDS (96 KB) for all 127 steps.
__global__ __launch_bounds__(512) void k_loop(
    const u16* __restrict__ sf_g, const f16* __restrict__ srch,
    const int* __restrict__ text, const float* __restrict__ embt,
    const f16* __restrict__ WhF, const float* __restrict__ bh2h,
    const float* __restrict__ wsc,
    const f16* __restrict__ WgF, const float* __restrict__ b_ih,
    const float* __restrict__ b_hh,
    float* __restrict__ cbuf,
    f16* __restrict__ X0, f16* __restrict__ X1, u16* __restrict__ hs,
    float* __restrict__ partial, float* __restrict__ ctx_part,
    float* __restrict__ s_part)
{
  cg::grid_group grid = cg::this_grid();
  extern __shared__ char smem[];
  f16*   sfl   = (f16*)(smem + SFL_OFF);     // [96*512]
  float* wsc_l = (float*)(smem + WSC_OFF);   // [512]
  char*  scr   = smem + SCR_OFF;

  const int tid  = threadIdx.x;
  const int w    = tid >> 6, lane = tid & 63;
  const int quad = lane >> 4, l16 = lane & 15;
  const int blk  = blockIdx.x;
  const int b    = blk >> 2, q = blk & 3;

  // -------- one-time preload: sf slice -> LDS, wscore -> LDS --------
  {
    const u16* gsf = sf_g + (size_t)(b*L_ + q*96)*512;
#pragma unroll
    for (int i=0;i<12;i++){
      int o = (i*512 + tid)*8;
      *(f16x8*)(sfl + o) = *(const f16x8*)((const f16*)gsf + o);
    }
    wsc_l[tid] = wsc[tid];
  }
  // all preloads complete before ANY aliased region (partial/hs) is written
  grid.sync();

  f16* Xg = X0; f16* Xn = X1;
  for (int t = 0; t < T_; ++t){
    // ================= Phase A: proj-sum + logits + exp + ctx partials =======
    {
      float* proj_l = (float*)scr;            // [512]
      float* cacc   = (float*)(scr + 2048);   // [8][512]
      float* ssum   = (float*)(scr + 18432);  // [8]
      {
        float p = bh2h[tid];
        if (t > 0){
#pragma unroll
          for (int jj=0; jj<16; jj++) p += partial[(size_t)jj*(64*512) + (size_t)b*512 + tid];
        }
        proj_l[tid] = p;
      }
      __syncthreads();
      float pr[8], wr8[8];
#pragma unroll
      for (int i=0;i<8;i++){ pr[i]=proj_l[lane*8+i]; wr8[i]=wsc_l[lane*8+i]; }
      float ctx8[8] = {0,0,0,0,0,0,0,0};
      float se = 0.f;
      for (int li=0; li<12; ++li){
        int lrow = w*12 + li;
        f16x8 rv = *(const f16x8*)(srch + (size_t)(b*L_ + q*96 + lrow)*512 + lane*8);
        f16x8 sv = *(const f16x8*)(sfl + lrow*512 + lane*8);
        float v = tanh_f((float)sv[0]+pr[0])*wr8[0] + tanh_f((float)sv[1]+pr[1])*wr8[1]
                + tanh_f((float)sv[2]+pr[2])*wr8[2] + tanh_f((float)sv[3]+pr[3])*wr8[3]
                + tanh_f((float)sv[4]+pr[4])*wr8[4] + tanh_f((float)sv[5]+pr[5])*wr8[5]
                + tanh_f((float)sv[6]+pr[6])*wr8[6] + tanh_f((float)sv[7]+pr[7])*wr8[7];
        v = wredsum_b(v);
        float e = __expf(v);   // |logit| bounded: no max-subtraction needed
        se += e;
#pragma unroll
        for (int i=0;i<8;i++) ctx8[i] += e*(float)rv[i];
      }
#pragma unroll
      for (int i=0;i<8;i++) cacc[w*512 + lane*8 + i] = ctx8[i];
      if (lane==0) ssum[w] = se;
      __syncthreads();
      {
        float cv = 0.f;
#pragma unroll
        for (int ww=0; ww<8; ww++) cv += cacc[ww*512 + tid];
        ctx_part[(size_t)blk*512 + tid] = cv;
        if (tid==0){
          float s=0.f;
#pragma unroll
          for (int ww=0; ww<8; ww++) s += ssum[ww];
          s_part[blk] = s;
        }
      }
    }
    grid.sync();
    // ================= Phase C: ctx combine + gates MFMA + cell + proj partials
    if (blk < 16){
      f16*   lctx = (f16*)scr;                   // [64][LPAD] = 33792 B
      float* gbuf = (float*)(scr + 33792);       // [4][64][16] = 16384 B
      f16*   h_sl = (f16*)(scr + 50176);         // [64][32] = 4096 B
      float* invs = (float*)(scr + 54272);       // [64]
      const int wv = w>>2, g = w&3;
      const int j2 = blk*2 + wv;
      if (tid < 64){
        float s = s_part[tid*4] + s_part[tid*4+1] + s_part[tid*4+2] + s_part[tid*4+3];
        invs[tid] = 1.f/s;
      }
      __syncthreads();
      f32x4 acc[4] = {};
      const f16* bp = WgF + (size_t)(g*512 + j2*16 + l16)*1280 + quad*8;
#pragma unroll
      for (int s=0; s<2; s++){
#pragma unroll
        for (int i=0;i<32;i++){
          int o = i*512 + tid;
          int b2 = o >> 8, cl = o & 255;
          int n = s*256 + cl;
          float cv = ctx_part[(size_t)(b2*4+0)*512+n] + ctx_part[(size_t)(b2*4+1)*512+n]
                   + ctx_part[(size_t)(b2*4+2)*512+n] + ctx_part[(size_t)(b2*4+3)*512+n];
          lctx[b2*LPAD + cl] = (f16)(cv * invs[b2]);
        }
        __syncthreads();
        for (int k0=0;k0<256;k0+=32){
          f16x8 bfr = *(const f16x8*)(bp + s*256 + k0);
#pragma unroll
          for (int f=0;f<4;f++){
            f16x8 afr = *(const f16x8*)(lctx + (f*16+l16)*LPAD + k0 + quad*8);
            acc[f] = __builtin_amdgcn_mfma_f32_16x16x32_f16(afr, bfr, acc[f], 0,0,0);
          }
        }
        __syncthreads();
      }
      for (int k0=512;k0<1280;k0+=32){
        f16x8 bfr = *(const f16x8*)(bp + k0);
#pragma unroll
        for (int f=0;f<4;f++){
          f16x8 afr = *(const f16x8*)(Xg + (size_t)(f*16+l16)*768 + (k0-512) + quad*8);
          acc[f] = __builtin_amdgcn_mfma_f32_16x16x32_f16(afr, bfr, acc[f], 0,0,0);
        }
      }
#pragma unroll
      for (int half=0; half<2; half++){
        if (wv == half){
#pragma unroll
          for (int f=0;f<4;f++)
#pragma unroll
            for (int r=0;r<4;r++)
              gbuf[g*1024 + (f*16+quad*4+r)*16 + l16] = acc[f][r];
        }
        __syncthreads();
#pragma unroll
        for (int i=0;i<2;i++){
          int cidx = tid + i*512;
          int b2 = cidx >> 4, hl = cidx & 15;
          int hg = (blk*2+half)*16 + hl;
          float gi = gbuf[0*1024 + b2*16+hl] + b_ih[hg]      + b_hh[hg];
          float gf = gbuf[1*1024 + b2*16+hl] + b_ih[512+hg]  + b_hh[512+hg];
          float gg = gbuf[2*1024 + b2*16+hl] + b_ih[1024+hg] + b_hh[1024+hg];
          float go = gbuf[3*1024 + b2*16+hl] + b_ih[1536+hg] + b_hh[1536+hg];
          float fi=sigm_f(gi), ff=sigm_f(gf), fg=tanh_f(gg), fo=sigm_f(go);
          size_t ci = ((size_t)b2<<9) + hg;
          float cn = ff*cbuf[ci] + fi*fg;
          float hn = fo*tanh_f(cn);
          cbuf[ci] = cn;
          Xn[(size_t)b2*768 + 256 + hg] = (f16)hn;
          hs[(((size_t)(b2*T_ + t))<<9) + hg] = f2h(hn);
          h_sl[b2*32 + half*16 + hl] = (f16)hn;
        }
        __syncthreads();
      }
      // proj(t+1) K-slice partials via MFMA on this block's 32-wide h slice
#pragma unroll
      for (int nt4=0; nt4<4; nt4++){
        int nt = w*4 + nt4;
        f16x8 bfr = *(const f16x8*)(WhF + (size_t)(nt*16+l16)*512 + blk*32 + quad*8);
#pragma unroll
        for (int mt=0; mt<4; mt++){
          f16x8 afr = *(const f16x8*)(h_sl + (mt*16+l16)*32 + quad*8);
          f32x4 pacc = {};
          pacc = __builtin_amdgcn_mfma_f32_16x16x32_f16(afr, bfr, pacc, 0,0,0);
#pragma unroll
          for (int r=0;r<4;r++)
            partial[(size_t)blk*(64*512) + (size_t)(mt*16+quad*4+r)*512 + nt*16+l16] = pacc[r];
        }
      }
    } else if (blk == 16 && (t+1) < T_){
#pragma unroll
      for (int i=0;i<32;i++){
        int e = tid + i*512;
        int b2 = e >> 8, col = e & 255;
        int tok = text[b2*T_ + t + 1];
        Xn[(size_t)b2*768 + col] = (f16)embt[(size_t)tok*E_ + col];
      }
    }
    grid.sync();
    f16* tmp = Xg; Xg = Xn; Xn = tmp;
  }
}

extern "C" void kernel_launch(void* const* d_in, const int* in_sizes, int n_in,
                              void* d_out, int out_size, void* d_ws, size_t ws_size,
                              hipStream_t stream)
{
  const float* src   = (const float*)d_in[0];
  const int*   text  = (const int*)d_in[1];
  const float* embt  = (const float*)d_in[2];
  const float* Wi2h  = (const float*)d_in[3];
  const float* Wh2h  = (const float*)d_in[4];
  const float* bh2h  = (const float*)d_in[5];
  const float* wsc   = (const float*)d_in[6];
  const float* W_ih  = (const float*)d_in[7];
  const float* b_ih  = (const float*)d_in[8];
  const float* W_hh  = (const float*)d_in[9];
  const float* b_hh  = (const float*)d_in[10];
  const float* Wgen  = (const float*)d_in[11];
  const float* bgen  = (const float*)d_in[12];
  float* out = (float*)d_out;

  // Workspace ~58 MB. ONLY partial and hs alias into the sf staging region:
  // both are first written in phase C of step 0, which is after the post-
  // preload grid.sync, so every block's sf slice is already LDS-resident.
  // ctx_part/s_part are written in phase A (step 0) -> they get their OWN
  // allocation (the round-7 aliasing of these raced with the preload).
  char* p = (char*)d_ws;
  u16*  sf      = (u16*)p;            p += (size_t)B_*L_*H_*2;      // 25.2 MB
  float* partial= (float*)sf;                                       // 2 MB alias
  u16*  hs      = (u16*)((char*)sf + 2097152);                      // 8.3 MB alias
  f16*  srch    = (f16*)p;            p += (size_t)B_*L_*CS*2;      // 25.2 MB
  f16*  WhF     = (f16*)p;            p += (size_t)H_*H_*2;         // 0.5 MB
  f16*  WgF     = (f16*)p;            p += (size_t)2048*1280*2;     // 5.2 MB
  f16*  X0      = (f16*)p;            p += (size_t)B_*768*2;        // 96 KB
  f16*  X1      = (f16*)p;            p += (size_t)B_*768*2;
  float* cbuf   = (float*)p;          p += (size_t)B_*H_*4;         // 128 KB
  float* ctxp   = (float*)p;          p += (size_t)256*512*4;       // 512 KB (no alias)
  float* s_part = (float*)p;          p += (size_t)256*4;           // 1 KB  (no alias)

  hipMemsetAsync(X0,   0, (size_t)B_*768*2, stream);
  hipMemsetAsync(cbuf, 0, (size_t)B_*H_*4, stream);

  k_cvt   <<<(H_*H_+255)/256, 256, 0, stream>>>(Wh2h, WhF, (size_t)H_*H_);
  k_cvt   <<<((size_t)B_*L_*CS+255)/256, 256, 0, stream>>>(src, srch, (size_t)B_*L_*CS);
  k_packwg<<<(2048*1280+255)/256, 256, 0, stream>>>(W_ih, W_hh, WgF);
  k_initx <<<B_, 256, 0, stream>>>(text, embt, X0);

  dim3 g1(B_*L_/128, H_/128);
  gemm_srcfeat<<<g1, 256, 0, stream>>>(src, Wi2h, sf, B_*L_, H_, CS);

  {
    hipFuncSetAttribute((const void*)k_loop,
        hipFuncAttributeMaxDynamicSharedMemorySize, LDS_TOTAL);
    const u16* sfp = sf;
    const f16* srchp = srch;
    u16* hsp = hs;
    void* kargs[] = {
      (void*)&sfp, (void*)&srchp, (void*)&text, (void*)&embt,
      (void*)&WhF, (void*)&bh2h, (void*)&wsc,
      (void*)&WgF, (void*)&b_ih, (void*)&b_hh,
      (void*)&cbuf, (void*)&X0, (void*)&X1, (void*)&hsp,
      (void*)&partial, (void*)&ctxp, (void*)&s_part
    };
    hipLaunchCooperativeKernel((const void*)k_loop, dim3(256), dim3(512),
                               kargs, LDS_TOTAL, stream);
  }

  dim3 g2(B_*T_/64, (NC+63)/64);
  gemm_probs<<<g2, 256, 0, stream>>>(hs, Wgen, bgen, out, B_*T_, NC, H_);
}